// Round 19
// baseline (240.020 us; speedup 1.0000x reference)
//
#include <hip/hip_runtime.h>
#include <stdint.h>

typedef _Float16 h2 __attribute__((ext_vector_type(2)));
typedef _Float16 h4 __attribute__((ext_vector_type(4)));
typedef float    f4 __attribute__((ext_vector_type(4)));

static constexpr int CDIM = 32;     // channels
static constexpr int NPIX = 16384;  // H*W = 128*128
static constexpr int SSAM = 1024;   // samples per row
static constexpr int NLOC = 625;    // 25x25 local-window prefix
static constexpr int NRND = SSAM - NLOC;   // 399 random samples
static constexpr int ROWS_PER_BLOCK = 16;  // rand path (8 pairs)

// LDS union layout (bytes):
//  dense: kslot[128*80]=10240 | res f16[4][16][128]=16384 @10240 |
//         wseg[1024] @26624 | rowacc f32[192] @27648 | end 28416
//  rand : idx int[2][2][448]=7168 @0 | bm u32[2][2][512]=8192 @7168 |
//         red f32[2][6][4]=192 @15360 | end 15552
static constexpr int SMEM_BYTES = 28416;

__device__ __forceinline__ uint16_t f2h(float f) {
    union { _Float16 h; uint16_t u; } c;
    c.h = (_Float16)f;
    return c.u;
}

template<int CTRL>
__device__ __forceinline__ float dpp_add(float x) {
    int y = __builtin_amdgcn_mov_dpp(__float_as_int(x), CTRL, 0xF, 0xF, true);
    return x + __int_as_float(y);
}

__device__ __forceinline__ float dot2(h2 a, h2 b, float c) {
    return __builtin_amdgcn_fdot2(a, b, c, false);   // v_dot2_f32_f16
}

// ---------------------------------------------------------------------------
// Kernel 1: layout prep. key/query [B][C][N] f32 -> [B*N][32] f16 rows (64B);
// query pre-scaled by C^-0.5. Emits seg8; zeroes segbit (2 words/thread).
// ---------------------------------------------------------------------------
__global__ __launch_bounds__(256)
void prep_kernel(const float* __restrict__ key_f,
                 const float* __restrict__ query_f,
                 const int* __restrict__ seg32,
                 uint8_t* __restrict__ key16,
                 uint8_t* __restrict__ q16,
                 uint8_t* __restrict__ seg8,
                 uint32_t* __restrict__ segbit,
                 int N, int rows, float scale)
{
    int gI = blockIdx.x * 256 + threadIdx.x;
    if (gI >= rows) return;
    segbit[2 * gI]     = 0;
    segbit[2 * gI + 1] = 0;
    seg8[gI] = (uint8_t)seg32[gI];

    int b = gI / N, n = gI - b * N;
    const size_t cb = (size_t)b * CDIM;

    uint32_t kp[16], qp[16];
#pragma unroll
    for (int c = 0; c < CDIM; c += 2) {
        float k0 = key_f[(cb + c) * N + n];
        float k1 = key_f[(cb + c + 1) * N + n];
        float q0 = query_f[(cb + c) * N + n] * scale;
        float q1 = query_f[(cb + c + 1) * N + n] * scale;
        kp[c >> 1] = (uint32_t)f2h(k0) | ((uint32_t)f2h(k1) << 16);
        qp[c >> 1] = (uint32_t)f2h(q0) | ((uint32_t)f2h(q1) << 16);
    }
    uint4* ko = (uint4*)(key16 + ((size_t)gI << 6));
    uint4* qo = (uint4*)(q16 + ((size_t)gI << 6));
#pragma unroll
    for (int j = 0; j < 4; ++j) {
        ko[j] = make_uint4(kp[4*j], kp[4*j+1], kp[4*j+2], kp[4*j+3]);
        qo[j] = make_uint4(qp[4*j], qp[4*j+1], qp[4*j+2], qp[4*j+3]);
    }
}

// ---------------------------------------------------------------------------
// Kernel 1b: segment bitmap. segbit[b][v][512]: bit n set iff seg[b][n]==v.
// ---------------------------------------------------------------------------
__global__ __launch_bounds__(256)
void segbit_build(const int* __restrict__ seg32,
                  uint32_t* __restrict__ segbit,
                  int N, int rows)
{
    int g = blockIdx.x * 256 + threadIdx.x;
    if (g >= rows) return;
    int b = g / N, n = g - b * N;
    int v = seg32[g] & 63;
    atomicOr(&segbit[(((size_t)(b * 64 + v)) << 9) + (n >> 5)], 1u << (n & 31));
}

// ---------------------------------------------------------------------------
// Dense path: local logits for s < 625, 4-row strips (LDS diet for fusion).
// Writes zA/tA/slA partials; no dependency on the rand path.
// ---------------------------------------------------------------------------
__device__ __forceinline__
void dense_path(uint8_t* smem, int bid,
                const uint8_t* __restrict__ key16,
                const uint8_t* __restrict__ q16,
                const uint8_t* __restrict__ seg8,
                float* __restrict__ out,
                float* __restrict__ zA,
                float* __restrict__ tA,
                float* __restrict__ slA)
{
    const int tid  = threadIdx.x;
    const int b    = bid >> 8;             // 256 tiles per image
    const int t8   = bid & 255;
    const int y0   = (t8 >> 4) << 3;
    const int x0   = (t8 & 15) << 3;
    const int lane = tid & 63;
    const int w    = tid >> 6;

    uint8_t*  kslot  = smem;                               // 10240B
    _Float16* res    = (_Float16*)(smem + 10240);          // [4][16][128]
    uint8_t*  wseg   = smem + 26624;                       // 1024B
    float*    rowacc = (float*)(smem + 27648);             // [4][16][3]

    const uint8_t* kb = key16 + ((size_t)b << 20);
    const uint8_t* sb = seg8 + ((size_t)b << 14);
    const int yo = y0 - 12, xo = x0 - 12;                  // unclamped origin

    for (int s = tid; s < 1024; s += 256) {
        int i = s >> 5, j = s & 31;
        int yy = min(max(yo + i, 0), 127);
        int xx = min(max(xo + j, 0), 127);
        wseg[s] = sb[(yy << 7) + xx];
    }
    if (tid < 192) rowacc[tid] = 0.f;

    const int qsel = (w << 4) + (lane & 15);
    const int qyA  = qsel >> 3, qxA = qsel & 7;
    const size_t qrow = ((size_t)b << 14) + ((size_t)(y0 + qyA) << 7) + (x0 + qxA);
    const int koff = (lane >> 4) << 3;                     // 8*(lane/16) bytes
    const h4 a0 = *(const h4*)(q16 + (qrow << 6) + koff);
    const h4 a1 = *(const h4*)(q16 + (qrow << 6) + 32 + koff);

    __syncthreads();    // wseg + rowacc visible

    for (int t = 0; t < 8; ++t) {           // 8 strips of 4 window rows
        // stage strip keys: 128 slots x 4 quarters = 512 uint4
        for (int s = tid; s < 512; s += 256) {
            int slot = s >> 2, q = s & 3;
            int i = (t << 2) + (slot >> 5), j = slot & 31;
            int yy = min(max(yo + i, 0), 127);
            int xx = min(max(xo + j, 0), 127);
            *(uint4*)(kslot + slot * 80 + (q << 4)) =
                *(const uint4*)(kb + ((((size_t)(yy << 7)) + xx) << 6) + (q << 4));
        }
        __syncthreads();

        // GEMM: 8 N-tiles of 16 slots
#pragma unroll
        for (int n = 0; n < 8; ++n) {
            const uint8_t* kr = kslot + ((n << 4) + (lane & 15)) * 80;
            h4 b0 = *(const h4*)(kr + koff);
            h4 b1 = *(const h4*)(kr + 32 + koff);
            f4 acc = {0.f, 0.f, 0.f, 0.f};
            acc = __builtin_amdgcn_mfma_f32_16x16x16f16(a0, b0, acc, 0, 0, 0);
            acc = __builtin_amdgcn_mfma_f32_16x16x16f16(a1, b1, acc, 0, 0, 0);
#pragma unroll
            for (int r = 0; r < 4; ++r) {
                int m = ((lane >> 4) << 2) + r;
                res[(w * 16 + m) * 128 + (n << 4) + (lane & 15)] =
                    (_Float16)acc[r];
            }
        }

        // selection: wave's 16 rows, <=100 samples per strip per row
        for (int m = 0; m < 16; ++m) {
            const int q  = (w << 4) + m;
            const int qy = q >> 3, qx = q & 7;
            const int row = (b << 14) + ((y0 + qy) << 7) + (x0 + qx);
            const int segr = (int)wseg[((qy + 12) << 5) + qx + 12];
            int sLo = ((t << 2) - qy) * 25; if (sLo < 0) sLo = 0;
            int sHi = ((t << 2) - qy + 4) * 25; if (sHi > NLOC) sHi = NLOC;
            float z = 0.f, tc = 0.f, sl = 0.f;
            for (int s = sLo + lane; s < sHi; s += 64) {
                int d25 = (s * 5243) >> 17;          // s/25 (exact for s<625)
                int r25 = s - d25 * 25;              // s%25
                int i  = qy + d25;                   // window row
                int wc = qx + r25;                   // window col
                float v = (float)res[(w * 16 + m) * 128 +
                                     (((i - (t << 2)) << 5) + wc)];
                out[((size_t)row << 10) + s] = v;
                z += __expf(v);
                if ((int)wseg[(i << 5) + wc] == segr) { tc += 1.f; sl += v; }
            }
#pragma unroll
            for (int off = 32; off >= 1; off >>= 1) {
                z  += __shfl_xor(z,  off, 64);
                tc += __shfl_xor(tc, off, 64);
                sl += __shfl_xor(sl, off, 64);
            }
            if (lane == 0) {
                rowacc[(w * 16 + m) * 3 + 0] += z;
                rowacc[(w * 16 + m) * 3 + 1] += tc;
                rowacc[(w * 16 + m) * 3 + 2] += sl;
            }
        }
        __syncthreads();    // all waves done before next strip restages kslot
    }

    if (tid < 64) {
        int q = tid, qy = q >> 3, qx = q & 7;
        int row = (b << 14) + ((y0 + qy) << 7) + (x0 + qx);
        zA[row]  = rowacc[q * 3 + 0];
        tA[row]  = rowacc[q * 3 + 1];
        slA[row] = rowacc[q * 3 + 2];
    }
}

// ---------------------------------------------------------------------------
// Rand path: gathered logits for s in [625,1024), paired rows (R15, fixed
// staging). Writes zB/tB/slB partials instead of final KL (decoupled).
// ---------------------------------------------------------------------------
__device__ __forceinline__
void rand_path(uint8_t* smem, int rbid,
               const int* __restrict__ inds,
               const uint8_t* __restrict__ key16,
               const uint8_t* __restrict__ q16,
               const int* __restrict__ seg32,
               const uint32_t* __restrict__ segbit,
               float* __restrict__ out,
               float* __restrict__ zB,
               float* __restrict__ tB,
               float* __restrict__ slB)
{
    const int tid  = threadIdx.x;
    const int row0 = rbid * ROWS_PER_BLOCK;
    const int b    = row0 >> 14;
    const int lane = tid & 63;
    const int w    = tid >> 6;
    const int g    = lane >> 2;
    const int sub  = lane & 3;
    const int gidx = (w << 4) + g;         // block-wide group 0..63
    const int half = tid >> 7;             // row within pair this thread stages
    const int ht   = tid & 127;

    int*      idxp = (int*)smem;                     // [2][2][448]
    uint32_t* bmp  = (uint32_t*)(smem + 7168);       // [2][2][512]
    float*    redp = (float*)(smem + 15360);         // [2][6][4]

    const uint32_t* sbm = segbit + ((size_t)(b * 64) << 9);

    {   // prologue: pair-0 staging (4 chunks cover all 399)
        const int* ib = inds + ((size_t)(row0 + half) << 10) + NLOC;
        int* d = idxp + half * 448;
        d[ht]       = ib[ht];
        d[ht + 128] = ib[ht + 128];
        d[ht + 256] = ib[ht + 256];
        if (ht < NRND - 384) d[ht + 384] = ib[ht + 384];
        int sh = seg32[row0 + half];
        ((uint4*)(bmp + half * 512))[ht] =
            ((const uint4*)(sbm + ((size_t)(sh & 63) << 9)))[ht];
    }
    int scurA = seg32[row0];
    int scurB = seg32[row0 + 1];
    uint4 qcurA = *(const uint4*)(q16 + ((size_t)row0 << 6) + (sub << 4));
    uint4 qcurB = *(const uint4*)(q16 + ((size_t)(row0 + 1) << 6) + (sub << 4));
    __syncthreads();

    const uint8_t* kp = key16 + ((size_t)b << 20);
    const uint32_t subs = (uint32_t)(sub << 4);
    const bool act6 = (384 + gidx) < NRND;              // gidx < 15
    const bool owned1 = (sub < 2) || (sub == 2 && act6);

    for (int t = 0; t < ROWS_PER_BLOCK / 2; ++t) {
        const int rowA = row0 + 2 * t;
        const int rowB = rowA + 1;
        const int pp   = t & 1;
        const int* curA = idxp + (pp * 2 + 0) * 448;
        const int* curB = idxp + (pp * 2 + 1) * 448;
        const uint32_t* bmA = bmp + (pp * 2 + 0) * 512;
        const uint32_t* bmB = bmp + (pp * 2 + 1) * 512;
        const bool hasNext = (t + 1 < ROWS_PER_BLOCK / 2);

        h2 qa0, qa1, qa2, qa3, qb0, qb1, qb2, qb3;
        {
            union { uint4 u; h2 h[4]; } qc;
            qc.u = qcurA; qa0 = qc.h[0]; qa1 = qc.h[1]; qa2 = qc.h[2]; qa3 = qc.h[3];
            qc.u = qcurB; qb0 = qc.h[0]; qb1 = qc.h[1]; qb2 = qc.h[2]; qb3 = qc.h[3];
        }

        // ---- indices for both rows ----
        int ixA[7], ixB[7];
#pragma unroll
        for (int i = 0; i < 7; ++i) {
            ixA[i] = curA[(i << 6) + gidx];
            ixB[i] = curB[(i << 6) + gidx];
        }

        // ---- 14 gathers (12 full + 2 tail-masked) ----
        uint4 ka[7], kb_[7];
#pragma unroll
        for (int i = 0; i < 6; ++i) {
            ka[i]  = *(const uint4*)(kp + (((uint32_t)ixA[i] << 6) | subs));
            kb_[i] = *(const uint4*)(kp + (((uint32_t)ixB[i] << 6) | subs));
        }
        ka[6] = make_uint4(0, 0, 0, 0);
        kb_[6] = make_uint4(0, 0, 0, 0);
        if (act6) {
            ka[6]  = *(const uint4*)(kp + (((uint32_t)ixA[6] << 6) | subs));
            kb_[6] = *(const uint4*)(kp + (((uint32_t)ixB[6] << 6) | subs));
        }

        // ---- latency cover: next-pair prefetch + target flags ----
        int pf0 = 0, pf1 = 0, pf2 = 0, pf3 = 0;
        uint4 bmn; int snA = 0, snB = 0;
        uint4 qnA, qnB;
        if (hasNext) {
            const int* ibn = inds + ((size_t)(rowA + 2 + half) << 10) + NLOC;
            pf0 = ibn[ht];
            pf1 = ibn[ht + 128];
            pf2 = ibn[ht + 256];
            if (ht < NRND - 384) pf3 = ibn[ht + 384];
            snA = seg32[rowA + 2];
            snB = seg32[rowA + 3];
            int sh = half ? snB : snA;
            bmn = ((const uint4*)(sbm + ((size_t)(sh & 63) << 9)))[ht];
            qnA = *(const uint4*)(q16 + ((size_t)(rowA + 2) << 6) + (sub << 4));
            qnB = *(const uint4*)(q16 + ((size_t)(rowA + 3) << 6) + (sub << 4));
        }
        int tfmA = 0, tfmB = 0;
        {
            int i0 = curA[(sub << 6) + gidx];
            if ((bmA[i0 >> 5] >> (i0 & 31)) & 1u) tfmA |= 1;
            int i1 = curB[(sub << 6) + gidx];
            if ((bmB[i1 >> 5] >> (i1 & 31)) & 1u) tfmB |= 1;
            if (sub < 3) {
                int j0 = curA[((sub + 4) << 6) + gidx];
                if (owned1 && ((bmA[j0 >> 5] >> (j0 & 31)) & 1u)) tfmA |= 2;
                int j1 = curB[((sub + 4) << 6) + gidx];
                if (owned1 && ((bmB[j1 >> 5] >> (j1 & 31)) & 1u)) tfmB |= 2;
            }
        }

        // ---- dots + quad reduce + owner capture + stores (both rows) ----
        const size_t obA = ((size_t)rowA << 10) + NLOC;
        const size_t obB = ((size_t)rowB << 10) + NLOC;
        float lgA0 = 0.f, lgA1 = 0.f, lgB0 = 0.f, lgB1 = 0.f;
#pragma unroll
        for (int it = 0; it < 7; ++it) {
            union { uint4 u; h2 h[4]; } kc;
            kc.u = ka[it];
            float aA = dot2(kc.h[0], qa0, 0.f);
            aA = dot2(kc.h[1], qa1, aA);
            aA = dot2(kc.h[2], qa2, aA);
            aA = dot2(kc.h[3], qa3, aA);
            kc.u = kb_[it];
            float aB = dot2(kc.h[0], qb0, 0.f);
            aB = dot2(kc.h[1], qb1, aB);
            aB = dot2(kc.h[2], qb2, aB);
            aB = dot2(kc.h[3], qb3, aB);
            aA = dpp_add<0xB1>(aA); aA = dpp_add<0x4E>(aA);
            aB = dpp_add<0xB1>(aB); aB = dpp_add<0x4E>(aB);
            if (sub == (it & 3)) {
                if (it < 4) { lgA0 = aA; lgB0 = aB; }
                else        { lgA1 = aA; lgB1 = aB; }
                if (it < 6 || act6) {
                    out[obA + (it << 6) + gidx] = aA;
                    out[obB + (it << 6) + gidx] = aB;
                }
            }
        }

        // ---- 6 parallel butterfly chains ----
        float z0 = __expf(lgA0) + (owned1 ? __expf(lgA1) : 0.f);
        float z1 = __expf(lgB0) + (owned1 ? __expf(lgB1) : 0.f);
        float c0 = (float)__popc((unsigned)tfmA);
        float c1 = (float)__popc((unsigned)tfmB);
        float s0 = ((tfmA & 1) ? lgA0 : 0.f) + ((tfmA & 2) ? lgA1 : 0.f);
        float s1 = ((tfmB & 1) ? lgB0 : 0.f) + ((tfmB & 2) ? lgB1 : 0.f);
#pragma unroll
        for (int off = 32; off >= 1; off >>= 1) {
            z0 += __shfl_xor(z0, off, 64);
            z1 += __shfl_xor(z1, off, 64);
            c0 += __shfl_xor(c0, off, 64);
            c1 += __shfl_xor(c1, off, 64);
            s0 += __shfl_xor(s0, off, 64);
            s1 += __shfl_xor(s1, off, 64);
        }
        if (lane == 0) {
            redp[(pp * 6 + 0) * 4 + w] = z0;
            redp[(pp * 6 + 1) * 4 + w] = c0;
            redp[(pp * 6 + 2) * 4 + w] = s0;
            redp[(pp * 6 + 3) * 4 + w] = z1;
            redp[(pp * 6 + 4) * 4 + w] = c1;
            redp[(pp * 6 + 5) * 4 + w] = s1;
        }

        // ---- commit prefetch into the other parity slots ----
        if (hasNext) {
            int* d = idxp + ((pp ^ 1) * 2 + half) * 448;
            d[ht]       = pf0;
            d[ht + 128] = pf1;
            d[ht + 256] = pf2;
            if (ht < NRND - 384) d[ht + 384] = pf3;
            ((uint4*)(bmp + ((pp ^ 1) * 2 + half) * 512))[ht] = bmn;
            qcurA = qnA; qcurB = qnB;
            scurA = snA; scurB = snB;
        }
        __syncthreads();                   // ONE barrier per pair

        if (tid < 2) {
            const int row  = rowA + tid;
            const int base = pp * 6 + tid * 3;
            zB[row]  = (redp[(base+0)*4+0] + redp[(base+0)*4+1]) +
                       (redp[(base+0)*4+2] + redp[(base+0)*4+3]);
            tB[row]  = (redp[(base+1)*4+0] + redp[(base+1)*4+1]) +
                       (redp[(base+1)*4+2] + redp[(base+1)*4+3]);
            slB[row] = (redp[(base+2)*4+0] + redp[(base+2)*4+1]) +
                       (redp[(base+2)*4+2] + redp[(base+2)*4+3]);
        }
    }
    (void)scurA; (void)scurB;
}

// ---------------------------------------------------------------------------
// Fused kernel with INTERLEAVED dispatch: dense:rand = 1:4 exactly, so
// bid%5==0 -> dense(bid/5), else rand(4*(bid/5) + bid%5 - 1). Each CU hosts
// a persistent dense/rand mix for the whole kernel (R18's split dispatch put
// all dense first -> no steady-state overlap). Falls back to split ordering
// if the 1:4 ratio doesn't hold.
// ---------------------------------------------------------------------------
__global__ __launch_bounds__(256)
void fused_affinity(const int* __restrict__ inds,
                    const uint8_t* __restrict__ key16,
                    const uint8_t* __restrict__ q16,
                    const uint8_t* __restrict__ seg8,
                    const int* __restrict__ seg32,
                    const uint32_t* __restrict__ segbit,
                    float* __restrict__ out,
                    float* __restrict__ zA, float* __restrict__ tA,
                    float* __restrict__ slA,
                    float* __restrict__ zB, float* __restrict__ tB,
                    float* __restrict__ slB,
                    int dense_blocks, int interleave)
{
    __shared__ __align__(16) uint8_t smem[SMEM_BYTES];
    const int bid = blockIdx.x;
    if (interleave) {
        const int grp = bid / 5, rem = bid - grp * 5;
        if (rem == 0)
            dense_path(smem, grp, key16, q16, seg8, out, zA, tA, slA);
        else
            rand_path(smem, 4 * grp + rem - 1, inds, key16, q16, seg32,
                      segbit, out, zB, tB, slB);
    } else {
        if (bid < dense_blocks)
            dense_path(smem, bid, key16, q16, seg8, out, zA, tA, slA);
        else
            rand_path(smem, bid - dense_blocks, inds, key16, q16, seg32,
                      segbit, out, zB, tB, slB);
    }
}

// ---------------------------------------------------------------------------
// Kernel 3: per-row closed-form KL from combined partials + deterministic
// single-block sum. loss = sum(-log T - SL/T + log Z) / count(seg!=0).
// ---------------------------------------------------------------------------
__global__ __launch_bounds__(1024)
void loss_combine(const float* __restrict__ zA, const float* __restrict__ tA,
                  const float* __restrict__ slA,
                  const float* __restrict__ zB, const float* __restrict__ tB,
                  const float* __restrict__ slB,
                  const int* __restrict__ seg32,
                  float* __restrict__ out_loss, int rows)
{
    const int tid = threadIdx.x;
    float s = 0.f, c = 0.f;
    for (int i = tid; i < rows; i += 1024) {
        if (seg32[i] != 0) {
            float Z  = zA[i] + zB[i];
            float T  = tA[i] + tB[i];   // >= 1 (center sample matches itself)
            float SL = slA[i] + slB[i];
            s += -__logf(T) - SL / T + __logf(Z);
            c += 1.f;
        }
    }
#pragma unroll
    for (int off = 32; off >= 1; off >>= 1) {
        s += __shfl_xor(s, off, 64);
        c += __shfl_xor(c, off, 64);
    }
    __shared__ float sA[16], sB[16];
    const int lane = tid & 63, wv = tid >> 6;
    if (lane == 0) { sA[wv] = s; sB[wv] = c; }
    __syncthreads();
    if (tid == 0) {
        float ts = 0.f, tc = 0.f;
#pragma unroll
        for (int k = 0; k < 16; ++k) { ts += sA[k]; tc += sB[k]; }
        out_loss[0] = ts / (tc + 1e-9f);
    }
}

// ---------------------------------------------------------------------------
// Fallback (generic shapes / tiny ws): per-thread gather from native layout.
// ---------------------------------------------------------------------------
__global__ __launch_bounds__(256)
void affinity_fallback(const float* __restrict__ key_f,
                       const float* __restrict__ query_f,
                       const int*   __restrict__ seg32,
                       const int*   __restrict__ inds,
                       float* __restrict__ out,
                       float* __restrict__ ws_kl,
                       int N, int S, float scale)
{
    const int bid = blockIdx.x;
    const int tid = threadIdx.x;
    const int b   = bid / N;

    __shared__ float q_lds[CDIM];
    __shared__ float redA[4], redB[4], redC[4];

    if (tid < CDIM) {
        int n = bid - b * N;
        q_lds[tid] = query_f[((size_t)(b * CDIM + tid)) * N + n];
    }
    const int seg_n = seg32[bid];
    __syncthreads();

    float q[CDIM];
#pragma unroll
    for (int c = 0; c < CDIM; ++c) q[c] = q_lds[c];

    const size_t rowbase = (size_t)bid * S;
    const int4 iv = ((const int4*)(inds + rowbase))[tid];
    const int idxv[4] = {iv.x, iv.y, iv.z, iv.w};

    float lg[4];
    int   tf[4];
#pragma unroll
    for (int k = 0; k < 4; ++k) {
        int idx = idxv[k];
        tf[k] = (seg32[b * N + idx] == seg_n) ? 1 : 0;
        float acc = 0.f;
#pragma unroll
        for (int c = 0; c < CDIM; ++c)
            acc = fmaf(key_f[((size_t)(b * CDIM + c)) * N + idx], q[c], acc);
        lg[k] = acc * scale;
    }
    ((float4*)(out + rowbase))[tid] = make_float4(lg[0], lg[1], lg[2], lg[3]);

    const int lane = tid & 63, wv = tid >> 6;
    float m = fmaxf(fmaxf(lg[0], lg[1]), fmaxf(lg[2], lg[3]));
#pragma unroll
    for (int off = 32; off >= 1; off >>= 1)
        m = fmaxf(m, __shfl_xor(m, off, 64));
    if (lane == 0) redA[wv] = m;
    __syncthreads();
    m = fmaxf(fmaxf(redA[0], redA[1]), fmaxf(redA[2], redA[3]));

    float e[4], z = 0.f, tcnt = 0.f;
#pragma unroll
    for (int k = 0; k < 4; ++k) {
        e[k] = expf(lg[k] - m);
        z += e[k];
        tcnt += (float)tf[k];
    }
#pragma unroll
    for (int off = 32; off >= 1; off >>= 1) {
        z    += __shfl_xor(z, off, 64);
        tcnt += __shfl_xor(tcnt, off, 64);
    }
    if (lane == 0) { redB[wv] = z; redC[wv] = tcnt; }
    __syncthreads();
    const float Z = redB[0] + redB[1] + redB[2] + redB[3];
    const float T = redC[0] + redC[1] + redC[2] + redC[3];

    float kl = 0.f;
    if (seg_n != 0) {
        const float invZ = 1.f / (Z + 1e-9f);
        const float invT = 1.f / (T + 1e-9f);
        const float nlT  = -logf(T + 1e-9f);
#pragma unroll
        for (int k = 0; k < 4; ++k) {
            if (tf[k]) {
                float p = e[k] * invZ;
                float yp = logf(fmaxf(p, 1e-8f));
                kl += invT * (nlT - yp);
            }
        }
    }
#pragma unroll
    for (int off = 32; off >= 1; off >>= 1)
        kl += __shfl_xor(kl, off, 64);
    if (lane == 0) redA[wv] = kl;
    __syncthreads();
    if (tid == 0)
        ws_kl[bid] = redA[0] + redA[1] + redA[2] + redA[3];
}

__global__ __launch_bounds__(1024)
void loss_reduce_fb(const float* __restrict__ ws_kl,
                    const int* __restrict__ seg32,
                    float* __restrict__ out_loss, int rows)
{
    const int tid = threadIdx.x;
    float s = 0.f, c = 0.f;
    for (int i = tid; i < rows; i += 1024) {
        s += ws_kl[i];
        c += (seg32[i] != 0) ? 1.f : 0.f;
    }
#pragma unroll
    for (int off = 32; off >= 1; off >>= 1) {
        s += __shfl_xor(s, off, 64);
        c += __shfl_xor(c, off, 64);
    }
    __shared__ float sA[16], sB[16];
    const int lane = tid & 63, wv = tid >> 6;
    if (lane == 0) { sA[wv] = s; sB[wv] = c; }
    __syncthreads();
    if (tid == 0) {
        float ts = 0.f, tc = 0.f;
#pragma unroll
        for (int k = 0; k < 16; ++k) { ts += sA[k]; tc += sB[k]; }
        out_loss[0] = ts / (tc + 1e-9f);
    }
}

// ---------------------------------------------------------------------------
extern "C" void kernel_launch(void* const* d_in, const int* in_sizes, int n_in,
                              void* d_out, int out_size, void* d_ws, size_t ws_size,
                              hipStream_t stream)
{
    const float* key_f   = (const float*)d_in[0];
    const float* query_f = (const float*)d_in[1];
    const int*   seg32   = (const int*)d_in[2];
    const int*   inds    = (const int*)d_in[3];
    float* out = (float*)d_out;

    const int N    = NPIX;
    const int rows = in_sizes[2];            // B*N
    const int S    = in_sizes[3] / rows;     // 1024
    const float scale = (float)(1.0 / sqrt((double)CDIM));
    const int B    = rows / N;

    // ws: key16 | q16 | seg8 | segbit | zA tA slA zB tB slB
    const size_t off_q16 = (size_t)rows * 64;
    const size_t off_s8  = off_q16 + (size_t)rows * 64;
    const size_t off_sb  = (off_s8 + (size_t)rows + 255) & ~(size_t)255;
    const size_t sb_words = (size_t)B * 64 * 512;     // == 2*rows
    const size_t off_arr = (off_sb + sb_words * 4 + 255) & ~(size_t)255;
    const size_t arr_sz  = (size_t)rows * 4;
    const size_t need    = off_arr + arr_sz * 6;

    uint8_t* wsb = (uint8_t*)d_ws;
    const bool geom_ok = (S == SSAM) && (rows % N == 0) &&
                         (rows % ROWS_PER_BLOCK == 0);

    if (ws_size >= need && geom_ok) {
        uint8_t*  key16  = wsb;
        uint8_t*  q16    = wsb + off_q16;
        uint8_t*  seg8   = wsb + off_s8;
        uint32_t* segbit = (uint32_t*)(wsb + off_sb);
        float*    zA     = (float*)(wsb + off_arr);
        float*    tA     = (float*)(wsb + off_arr + arr_sz);
        float*    slA    = (float*)(wsb + off_arr + arr_sz * 2);
        float*    zB     = (float*)(wsb + off_arr + arr_sz * 3);
        float*    tB     = (float*)(wsb + off_arr + arr_sz * 4);
        float*    slB    = (float*)(wsb + off_arr + arr_sz * 5);

        const int dense_blocks = B * 256;
        const int rand_blocks  = rows / ROWS_PER_BLOCK;
        const int interleave   = (rand_blocks == 4 * dense_blocks) ? 1 : 0;

        prep_kernel<<<(rows + 255) / 256, 256, 0, stream>>>(
            key_f, query_f, seg32, key16, q16, seg8, segbit, N, rows, scale);
        segbit_build<<<(rows + 255) / 256, 256, 0, stream>>>(
            seg32, segbit, N, rows);
        fused_affinity<<<dense_blocks + rand_blocks, 256, 0, stream>>>(
            inds, key16, q16, seg8, seg32, segbit, out,
            zA, tA, slA, zB, tB, slB, dense_blocks, interleave);
        loss_combine<<<1, 1024, 0, stream>>>(
            zA, tA, slA, zB, tB, slB, seg32, out + (size_t)rows * S, rows);
    } else {
        float* wskl = (float*)d_ws;
        affinity_fallback<<<rows, 256, 0, stream>>>(
            key_f, query_f, seg32, inds, out, wskl, N, S, scale);
        loss_reduce_fb<<<1, 1024, 0, stream>>>(
            wskl, seg32, out + (size_t)rows * S, rows);
    }
}

// Round 20
// 163.640 us; speedup vs baseline: 1.4668x; 1.4668x over previous
//
#include <hip/hip_runtime.h>
#include <stdint.h>

typedef _Float16 h2 __attribute__((ext_vector_type(2)));
typedef _Float16 h4 __attribute__((ext_vector_type(4)));
typedef float    f4 __attribute__((ext_vector_type(4)));

static constexpr int CDIM = 32;     // channels
static constexpr int NPIX = 16384;  // H*W = 128*128
static constexpr int SSAM = 1024;   // samples per row
static constexpr int NLOC = 625;    // 25x25 local-window prefix
static constexpr int NRND = SSAM - NLOC;   // 399 random samples
static constexpr int ROWS_PER_BLOCK = 16;  // gather kernel (8 pairs)

__device__ __forceinline__ uint16_t f2h(float f) {
    union { _Float16 h; uint16_t u; } c;
    c.h = (_Float16)f;
    return c.u;
}

template<int CTRL>
__device__ __forceinline__ float dpp_add(float x) {
    int y = __builtin_amdgcn_mov_dpp(__float_as_int(x), CTRL, 0xF, 0xF, true);
    return x + __int_as_float(y);
}

__device__ __forceinline__ float dot2(h2 a, h2 b, float c) {
    return __builtin_amdgcn_fdot2(a, b, c, false);   // v_dot2_f32_f16
}

// ---------------------------------------------------------------------------
// Kernel 1: layout prep. key/query [B][C][N] f32 -> [B*N][32] f16 rows (64B);
// query pre-scaled by C^-0.5. Emits seg8; zeroes segbit (2 words/thread).
// ---------------------------------------------------------------------------
__global__ __launch_bounds__(256)
void prep_kernel(const float* __restrict__ key_f,
                 const float* __restrict__ query_f,
                 const int* __restrict__ seg32,
                 uint8_t* __restrict__ key16,
                 uint8_t* __restrict__ q16,
                 uint8_t* __restrict__ seg8,
                 uint32_t* __restrict__ segbit,
                 int N, int rows, float scale)
{
    int gI = blockIdx.x * 256 + threadIdx.x;
    if (gI >= rows) return;
    segbit[2 * gI]     = 0;
    segbit[2 * gI + 1] = 0;
    seg8[gI] = (uint8_t)seg32[gI];

    int b = gI / N, n = gI - b * N;
    const size_t cb = (size_t)b * CDIM;

    uint32_t kp[16], qp[16];
#pragma unroll
    for (int c = 0; c < CDIM; c += 2) {
        float k0 = key_f[(cb + c) * N + n];
        float k1 = key_f[(cb + c + 1) * N + n];
        float q0 = query_f[(cb + c) * N + n] * scale;
        float q1 = query_f[(cb + c + 1) * N + n] * scale;
        kp[c >> 1] = (uint32_t)f2h(k0) | ((uint32_t)f2h(k1) << 16);
        qp[c >> 1] = (uint32_t)f2h(q0) | ((uint32_t)f2h(q1) << 16);
    }
    uint4* ko = (uint4*)(key16 + ((size_t)gI << 6));
    uint4* qo = (uint4*)(q16 + ((size_t)gI << 6));
#pragma unroll
    for (int j = 0; j < 4; ++j) {
        ko[j] = make_uint4(kp[4*j], kp[4*j+1], kp[4*j+2], kp[4*j+3]);
        qo[j] = make_uint4(qp[4*j], qp[4*j+1], qp[4*j+2], qp[4*j+3]);
    }
}

// ---------------------------------------------------------------------------
// Kernel 1b: segment bitmap. segbit[b][v][512]: bit n set iff seg[b][n]==v.
// ---------------------------------------------------------------------------
__global__ __launch_bounds__(256)
void segbit_build(const int* __restrict__ seg32,
                  uint32_t* __restrict__ segbit,
                  int N, int rows)
{
    int g = blockIdx.x * 256 + threadIdx.x;
    if (g >= rows) return;
    int b = g / N, n = g - b * N;
    int v = seg32[g] & 63;
    atomicOr(&segbit[(((size_t)(b * 64 + v)) << 9) + (n >> 5)], 1u << (n & 31));
}

// ---------------------------------------------------------------------------
// Kernel A: dense local logits for s < 625 (full 25x25 local window prefix).
// One block per 8x8 query tile; clamped 32x32 key window staged strip-by-
// strip (8 rows = 20KB); 64x256x32 GEMM per strip via 2x
// v_mfma_f32_16x16x16_f16; results in wave-private f16 LDS (32KB). Total
// LDS ~54KB -> 2 blocks/CU. Best-measured configuration (R16: 165.46us).
// ---------------------------------------------------------------------------
__global__ __launch_bounds__(256)
void dense_local(const uint8_t* __restrict__ key16,
                 const uint8_t* __restrict__ q16,
                 const uint8_t* __restrict__ seg8,
                 float* __restrict__ out,
                 float* __restrict__ zA,
                 float* __restrict__ tA,
                 float* __restrict__ slA)
{
    const int tid  = threadIdx.x;
    const int bid  = blockIdx.x;
    const int b    = bid >> 8;             // 256 tiles per image
    const int t8   = bid & 255;
    const int y0   = (t8 >> 4) << 3;
    const int x0   = (t8 & 15) << 3;
    const int lane = tid & 63;
    const int w    = tid >> 6;

    __shared__ __align__(16) uint8_t  kslot[256 * 80];    // 20KB strip keys
    __shared__ __align__(16) _Float16 res[4][16][256];    // 32KB wave-private
    __shared__ uint8_t wseg[1024];                        // window seg
    __shared__ float   rowacc[4][16][3];                  // Z,T,SL per query

    const uint8_t* kb = key16 + ((size_t)b << 20);
    const uint8_t* sb = seg8 + ((size_t)b << 14);
    const int yo = y0 - 12, xo = x0 - 12;                 // unclamped origin

    for (int s = tid; s < 1024; s += 256) {
        int i = s >> 5, j = s & 31;
        int yy = min(max(yo + i, 0), 127);
        int xx = min(max(xo + j, 0), 127);
        wseg[s] = sb[(yy << 7) + xx];
    }
    if (tid < 192) ((float*)rowacc)[tid] = 0.f;

    const int qsel = (w << 4) + (lane & 15);
    const int qyA  = qsel >> 3, qxA = qsel & 7;
    const size_t qrow = ((size_t)b << 14) + ((size_t)(y0 + qyA) << 7) + (x0 + qxA);
    const int koff = (lane >> 4) << 3;                    // 8*(lane/16) bytes
    const h4 a0 = *(const h4*)(q16 + (qrow << 6) + koff);
    const h4 a1 = *(const h4*)(q16 + (qrow << 6) + 32 + koff);

    __syncthreads();

    for (int t = 0; t < 4; ++t) {
        for (int s = tid; s < 1024; s += 256) {
            int slot = s >> 2, q = s & 3;
            int i = (t << 3) + (slot >> 5), j = slot & 31;
            int yy = min(max(yo + i, 0), 127);
            int xx = min(max(xo + j, 0), 127);
            *(uint4*)(kslot + slot * 80 + (q << 4)) =
                *(const uint4*)(kb + ((((size_t)(yy << 7)) + xx) << 6) + (q << 4));
        }
        __syncthreads();

#pragma unroll 4
        for (int n = 0; n < 16; ++n) {
            const uint8_t* kr = kslot + ((n << 4) + (lane & 15)) * 80;
            h4 b0 = *(const h4*)(kr + koff);
            h4 b1 = *(const h4*)(kr + 32 + koff);
            f4 acc = {0.f, 0.f, 0.f, 0.f};
            acc = __builtin_amdgcn_mfma_f32_16x16x16f16(a0, b0, acc, 0, 0, 0);
            acc = __builtin_amdgcn_mfma_f32_16x16x16f16(a1, b1, acc, 0, 0, 0);
#pragma unroll
            for (int r = 0; r < 4; ++r)
                res[w][((lane >> 4) << 2) + r][(n << 4) + (lane & 15)] =
                    (_Float16)acc[r];
        }

        for (int m = 0; m < 16; ++m) {
            const int q  = (w << 4) + m;
            const int qy = q >> 3, qx = q & 7;
            const int row = (b << 14) + ((y0 + qy) << 7) + (x0 + qx);
            const int segr = (int)wseg[((qy + 12) << 5) + qx + 12];
            int sLo = ((t << 3) - qy) * 25; if (sLo < 0) sLo = 0;
            int sHi = ((t << 3) - qy + 8) * 25; if (sHi > NLOC) sHi = NLOC;
            float z = 0.f, tc = 0.f, sl = 0.f;
            for (int s = sLo + lane; s < sHi; s += 64) {
                int d25 = (s * 5243) >> 17;          // s/25 (exact here)
                int r25 = s - d25 * 25;              // s%25
                int i  = qy + d25;
                int wc = qx + r25;
                float v = (float)res[w][m][((i - (t << 3)) << 5) + wc];
                out[((size_t)row << 10) + s] = v;
                z += __expf(v);
                if ((int)wseg[(i << 5) + wc] == segr) { tc += 1.f; sl += v; }
            }
#pragma unroll
            for (int off = 32; off >= 1; off >>= 1) {
                z  += __shfl_xor(z,  off, 64);
                tc += __shfl_xor(tc, off, 64);
                sl += __shfl_xor(sl, off, 64);
            }
            if (lane == 0) {
                rowacc[w][m][0] += z;
                rowacc[w][m][1] += tc;
                rowacc[w][m][2] += sl;
            }
        }
        __syncthreads();
    }

    if (tid < 64) {
        int q = tid, qy = q >> 3, qx = q & 7;
        int row = (b << 14) + ((y0 + qy) << 7) + (x0 + qx);
        zA[row]  = rowacc[q >> 4][q & 15][0];
        tA[row]  = rowacc[q >> 4][q & 15][1];
        slA[row] = rowacc[q >> 4][q & 15][2];
    }
}

// ---------------------------------------------------------------------------
// Kernel B: gathered logits for s in [625,1024), PAIRED ROWS (R16 config).
// 2 rows/iter: half-block staging (4 chunks cover all 399), 14 shared-window
// gathers, 6 parallel butterfly chains, ONE barrier per pair, tid 0/1
// finalize both KLs (closed-form, merged with dense partials).
// ---------------------------------------------------------------------------
__global__ __launch_bounds__(256)
void affinity_rand(const int* __restrict__ inds,
                   const uint8_t* __restrict__ key16,
                   const uint8_t* __restrict__ q16,
                   const int* __restrict__ seg32,
                   const uint32_t* __restrict__ segbit,
                   const float* __restrict__ zA,
                   const float* __restrict__ tA,
                   const float* __restrict__ slA,
                   float* __restrict__ out,
                   float* __restrict__ ws_kl)
{
    const int tid  = threadIdx.x;
    const int row0 = blockIdx.x * ROWS_PER_BLOCK;
    const int b    = row0 >> 14;
    const int lane = tid & 63;
    const int w    = tid >> 6;
    const int g    = lane >> 2;
    const int sub  = lane & 3;
    const int gidx = (w << 4) + g;         // block-wide group 0..63
    const int half = tid >> 7;             // row within pair this thread stages
    const int ht   = tid & 127;

    __shared__ __align__(16) int      idx_lds[2][2][448];  // [pairpar][row][s]
    __shared__ __align__(16) uint32_t bm_lds[2][2][512];
    __shared__ float red[2][6][4];         // [pairpar][ZTS x 2 rows][wave]
    __shared__ float zp[ROWS_PER_BLOCK], tp[ROWS_PER_BLOCK], sp[ROWS_PER_BLOCK];

    const uint32_t* sbm = segbit + ((size_t)(b * 64) << 9);

    // prologue: dense partials + pair-0 state
    if (tid < ROWS_PER_BLOCK)             zp[tid] = zA[row0 + tid];
    else if (tid < 2*ROWS_PER_BLOCK)      tp[tid - ROWS_PER_BLOCK] = tA[row0 + tid - ROWS_PER_BLOCK];
    else if (tid < 3*ROWS_PER_BLOCK)      sp[tid - 2*ROWS_PER_BLOCK] = slA[row0 + tid - 2*ROWS_PER_BLOCK];

    {
        const int* ib = inds + ((size_t)(row0 + half) << 10) + NLOC;
        idx_lds[0][half][ht]       = ib[ht];
        idx_lds[0][half][ht + 128] = ib[ht + 128];
        idx_lds[0][half][ht + 256] = ib[ht + 256];          // 256..383 (<399)
        if (ht < NRND - 384)                                 // 384..398
            idx_lds[0][half][ht + 384] = ib[ht + 384];
        int sh = seg32[row0 + half];
        ((uint4*)bm_lds[0][half])[ht] =
            ((const uint4*)(sbm + ((size_t)(sh & 63) << 9)))[ht];
    }
    int scurA = seg32[row0];
    int scurB = seg32[row0 + 1];
    uint4 qcurA = *(const uint4*)(q16 + ((size_t)row0 << 6) + (sub << 4));
    uint4 qcurB = *(const uint4*)(q16 + ((size_t)(row0 + 1) << 6) + (sub << 4));
    __syncthreads();

    const uint8_t* kp = key16 + ((size_t)b << 20);
    const uint32_t subs = (uint32_t)(sub << 4);
    const bool act6 = (384 + gidx) < NRND;              // gidx < 15
    const bool owned1 = (sub < 2) || (sub == 2 && act6);

    for (int t = 0; t < ROWS_PER_BLOCK / 2; ++t) {
        const int rowA = row0 + 2 * t;
        const int rowB = rowA + 1;
        const int pp   = t & 1;
        const int* curA = idx_lds[pp][0];
        const int* curB = idx_lds[pp][1];
        const bool hasNext = (t + 1 < ROWS_PER_BLOCK / 2);

        h2 qa0, qa1, qa2, qa3, qb0, qb1, qb2, qb3;
        {
            union { uint4 u; h2 h[4]; } qc;
            qc.u = qcurA; qa0 = qc.h[0]; qa1 = qc.h[1]; qa2 = qc.h[2]; qa3 = qc.h[3];
            qc.u = qcurB; qb0 = qc.h[0]; qb1 = qc.h[1]; qb2 = qc.h[2]; qb3 = qc.h[3];
        }
        const int segA = scurA, segB = scurB;

        // ---- indices for both rows ----
        int ixA[7], ixB[7];
#pragma unroll
        for (int i = 0; i < 7; ++i) {
            ixA[i] = curA[(i << 6) + gidx];
            ixB[i] = curB[(i << 6) + gidx];
        }

        // ---- 14 gathers (12 full + 2 tail-masked) ----
        uint4 ka[7], kb_[7];
#pragma unroll
        for (int i = 0; i < 6; ++i) {
            ka[i]  = *(const uint4*)(kp + (((uint32_t)ixA[i] << 6) | subs));
            kb_[i] = *(const uint4*)(kp + (((uint32_t)ixB[i] << 6) | subs));
        }
        ka[6] = make_uint4(0, 0, 0, 0);
        kb_[6] = make_uint4(0, 0, 0, 0);
        if (act6) {
            ka[6]  = *(const uint4*)(kp + (((uint32_t)ixA[6] << 6) | subs));
            kb_[6] = *(const uint4*)(kp + (((uint32_t)ixB[6] << 6) | subs));
        }

        // ---- latency cover: next-pair prefetch + target flags ----
        int pf0 = 0, pf1 = 0, pf2 = 0, pf3 = 0;
        uint4 bmn; int snA = 0, snB = 0;
        uint4 qnA, qnB;
        if (hasNext) {
            const int* ibn = inds + ((size_t)(rowA + 2 + half) << 10) + NLOC;
            pf0 = ibn[ht];
            pf1 = ibn[ht + 128];
            pf2 = ibn[ht + 256];
            if (ht < NRND - 384) pf3 = ibn[ht + 384];
            snA = seg32[rowA + 2];
            snB = seg32[rowA + 3];
            int sh = half ? snB : snA;
            bmn = ((const uint4*)(sbm + ((size_t)(sh & 63) << 9)))[ht];
            qnA = *(const uint4*)(q16 + ((size_t)(rowA + 2) << 6) + (sub << 4));
            qnB = *(const uint4*)(q16 + ((size_t)(rowA + 3) << 6) + (sub << 4));
        }
        int tfmA = 0, tfmB = 0;
        {
            int i0 = curA[(sub << 6) + gidx];
            if ((bm_lds[pp][0][i0 >> 5] >> (i0 & 31)) & 1u) tfmA |= 1;
            int i1 = curB[(sub << 6) + gidx];
            if ((bm_lds[pp][1][i1 >> 5] >> (i1 & 31)) & 1u) tfmB |= 1;
            if (sub < 3) {
                int j0 = curA[((sub + 4) << 6) + gidx];
                if (owned1 && ((bm_lds[pp][0][j0 >> 5] >> (j0 & 31)) & 1u)) tfmA |= 2;
                int j1 = curB[((sub + 4) << 6) + gidx];
                if (owned1 && ((bm_lds[pp][1][j1 >> 5] >> (j1 & 31)) & 1u)) tfmB |= 2;
            }
        }

        // ---- dots + quad reduce + owner capture + stores (both rows) ----
        const size_t obA = ((size_t)rowA << 10) + NLOC;
        const size_t obB = ((size_t)rowB << 10) + NLOC;
        float lgA0 = 0.f, lgA1 = 0.f, lgB0 = 0.f, lgB1 = 0.f;
#pragma unroll
        for (int it = 0; it < 7; ++it) {
            union { uint4 u; h2 h[4]; } kc;
            kc.u = ka[it];
            float aA = dot2(kc.h[0], qa0, 0.f);
            aA = dot2(kc.h[1], qa1, aA);
            aA = dot2(kc.h[2], qa2, aA);
            aA = dot2(kc.h[3], qa3, aA);
            kc.u = kb_[it];
            float aB = dot2(kc.h[0], qb0, 0.f);
            aB = dot2(kc.h[1], qb1, aB);
            aB = dot2(kc.h[2], qb2, aB);
            aB = dot2(kc.h[3], qb3, aB);
            aA = dpp_add<0xB1>(aA); aA = dpp_add<0x4E>(aA);
            aB = dpp_add<0xB1>(aB); aB = dpp_add<0x4E>(aB);
            if (sub == (it & 3)) {
                if (it < 4) { lgA0 = aA; lgB0 = aB; }
                else        { lgA1 = aA; lgB1 = aB; }
                if (it < 6 || act6) {
                    out[obA + (it << 6) + gidx] = aA;
                    out[obB + (it << 6) + gidx] = aB;
                }
            }
        }

        // ---- 6 parallel butterfly chains ----
        float z0 = __expf(lgA0) + (owned1 ? __expf(lgA1) : 0.f);
        float z1 = __expf(lgB0) + (owned1 ? __expf(lgB1) : 0.f);
        float c0 = (float)__popc((unsigned)tfmA);
        float c1 = (float)__popc((unsigned)tfmB);
        float s0 = ((tfmA & 1) ? lgA0 : 0.f) + ((tfmA & 2) ? lgA1 : 0.f);
        float s1 = ((tfmB & 1) ? lgB0 : 0.f) + ((tfmB & 2) ? lgB1 : 0.f);
#pragma unroll
        for (int off = 32; off >= 1; off >>= 1) {
            z0 += __shfl_xor(z0, off, 64);
            z1 += __shfl_xor(z1, off, 64);
            c0 += __shfl_xor(c0, off, 64);
            c1 += __shfl_xor(c1, off, 64);
            s0 += __shfl_xor(s0, off, 64);
            s1 += __shfl_xor(s1, off, 64);
        }
        if (lane == 0) {
            red[pp][0][w] = z0; red[pp][1][w] = c0; red[pp][2][w] = s0;
            red[pp][3][w] = z1; red[pp][4][w] = c1; red[pp][5][w] = s1;
        }

        // ---- commit prefetch into the other parity slots ----
        if (hasNext) {
            idx_lds[pp ^ 1][half][ht]       = pf0;
            idx_lds[pp ^ 1][half][ht + 128] = pf1;
            idx_lds[pp ^ 1][half][ht + 256] = pf2;
            if (ht < NRND - 384) idx_lds[pp ^ 1][half][ht + 384] = pf3;
            ((uint4*)bm_lds[pp ^ 1][half])[ht] = bmn;
            qcurA = qnA; qcurB = qnB;
            scurA = snA; scurB = snB;
        }
        __syncthreads();                   // ONE barrier per pair

        if (tid < 2) {
            const int  row  = rowA + tid;
            const int  sgn  = tid ? segB : segA;
            const int  base = tid * 3;
            if (sgn != 0) {
                const float Z  = zp[2*t + tid] +
                    (red[pp][base][0] + red[pp][base][1]) + (red[pp][base][2] + red[pp][base][3]);
                const float T  = tp[2*t + tid] +
                    (red[pp][base+1][0] + red[pp][base+1][1]) + (red[pp][base+1][2] + red[pp][base+1][3]);
                const float SL = sp[2*t + tid] +
                    (red[pp][base+2][0] + red[pp][base+2][1]) + (red[pp][base+2][2] + red[pp][base+2][3]);
                // closed-form KL; T >= 1 (center sample matches itself)
                ws_kl[row] = -__logf(T) - SL / T + __logf(Z);
            } else {
                ws_kl[row] = 0.f;
            }
        }
    }
}

// ---------------------------------------------------------------------------
// Fallback (generic shapes / tiny ws): per-thread gather from native layout.
// ---------------------------------------------------------------------------
__global__ __launch_bounds__(256)
void affinity_fallback(const float* __restrict__ key_f,
                       const float* __restrict__ query_f,
                       const int*   __restrict__ seg32,
                       const int*   __restrict__ inds,
                       float* __restrict__ out,
                       float* __restrict__ ws_kl,
                       int N, int S, float scale)
{
    const int bid = blockIdx.x;
    const int tid = threadIdx.x;
    const int b   = bid / N;

    __shared__ float q_lds[CDIM];
    __shared__ float redA[4], redB[4], redC[4];

    if (tid < CDIM) {
        int n = bid - b * N;
        q_lds[tid] = query_f[((size_t)(b * CDIM + tid)) * N + n];
    }
    const int seg_n = seg32[bid];
    __syncthreads();

    float q[CDIM];
#pragma unroll
    for (int c = 0; c < CDIM; ++c) q[c] = q_lds[c];

    const size_t rowbase = (size_t)bid * S;
    const int4 iv = ((const int4*)(inds + rowbase))[tid];
    const int idxv[4] = {iv.x, iv.y, iv.z, iv.w};

    float lg[4];
    int   tf[4];
#pragma unroll
    for (int k = 0; k < 4; ++k) {
        int idx = idxv[k];
        tf[k] = (seg32[b * N + idx] == seg_n) ? 1 : 0;
        float acc = 0.f;
#pragma unroll
        for (int c = 0; c < CDIM; ++c)
            acc = fmaf(key_f[((size_t)(b * CDIM + c)) * N + idx], q[c], acc);
        lg[k] = acc * scale;
    }
    ((float4*)(out + rowbase))[tid] = make_float4(lg[0], lg[1], lg[2], lg[3]);

    const int lane = tid & 63, wv = tid >> 6;
    float m = fmaxf(fmaxf(lg[0], lg[1]), fmaxf(lg[2], lg[3]));
#pragma unroll
    for (int off = 32; off >= 1; off >>= 1)
        m = fmaxf(m, __shfl_xor(m, off, 64));
    if (lane == 0) redA[wv] = m;
    __syncthreads();
    m = fmaxf(fmaxf(redA[0], redA[1]), fmaxf(redA[2], redA[3]));

    float e[4], z = 0.f, tcnt = 0.f;
#pragma unroll
    for (int k = 0; k < 4; ++k) {
        e[k] = expf(lg[k] - m);
        z += e[k];
        tcnt += (float)tf[k];
    }
#pragma unroll
    for (int off = 32; off >= 1; off >>= 1) {
        z    += __shfl_xor(z, off, 64);
        tcnt += __shfl_xor(tcnt, off, 64);
    }
    if (lane == 0) { redB[wv] = z; redC[wv] = tcnt; }
    __syncthreads();
    const float Z = redB[0] + redB[1] + redB[2] + redB[3];
    const float T = redC[0] + redC[1] + redC[2] + redC[3];

    float kl = 0.f;
    if (seg_n != 0) {
        const float invZ = 1.f / (Z + 1e-9f);
        const float invT = 1.f / (T + 1e-9f);
        const float nlT  = -logf(T + 1e-9f);
#pragma unroll
        for (int k = 0; k < 4; ++k) {
            if (tf[k]) {
                float p = e[k] * invZ;
                float yp = logf(fmaxf(p, 1e-8f));
                kl += invT * (nlT - yp);
            }
        }
    }
#pragma unroll
    for (int off = 32; off >= 1; off >>= 1)
        kl += __shfl_xor(kl, off, 64);
    if (lane == 0) redA[wv] = kl;
    __syncthreads();
    if (tid == 0)
        ws_kl[bid] = redA[0] + redA[1] + redA[2] + redA[3];
}

// ---------------------------------------------------------------------------
// Kernel 3: deterministic single-block loss reduction (1024 threads).
// ---------------------------------------------------------------------------
__global__ __launch_bounds__(1024)
void loss_reduce(const float* __restrict__ ws_kl,
                 const int* __restrict__ seg32,
                 float* __restrict__ out_loss, int rows)
{
    const int tid = threadIdx.x;
    float s = 0.f, c = 0.f;
    for (int i = tid; i < rows; i += 1024) {
        s += ws_kl[i];
        c += (seg32[i] != 0) ? 1.f : 0.f;
    }
#pragma unroll
    for (int off = 32; off >= 1; off >>= 1) {
        s += __shfl_xor(s, off, 64);
        c += __shfl_xor(c, off, 64);
    }
    __shared__ float sA[16], sB[16];
    const int lane = tid & 63, wv = tid >> 6;
    if (lane == 0) { sA[wv] = s; sB[wv] = c; }
    __syncthreads();
    if (tid == 0) {
        float ts = 0.f, tc = 0.f;
#pragma unroll
        for (int k = 0; k < 16; ++k) { ts += sA[k]; tc += sB[k]; }
        out_loss[0] = ts / (tc + 1e-9f);
    }
}

// ---------------------------------------------------------------------------
extern "C" void kernel_launch(void* const* d_in, const int* in_sizes, int n_in,
                              void* d_out, int out_size, void* d_ws, size_t ws_size,
                              hipStream_t stream)
{
    const float* key_f   = (const float*)d_in[0];
    const float* query_f = (const float*)d_in[1];
    const int*   seg32   = (const int*)d_in[2];
    const int*   inds    = (const int*)d_in[3];
    float* out = (float*)d_out;

    const int N    = NPIX;
    const int rows = in_sizes[2];            // B*N
    const int S    = in_sizes[3] / rows;     // 1024
    const float scale = (float)(1.0 / sqrt((double)CDIM));
    const int B    = rows / N;

    // ws: key16 | q16 | seg8 | segbit | zA | tA | slA | kl
    const size_t off_q16 = (size_t)rows * 64;
    const size_t off_s8  = off_q16 + (size_t)rows * 64;
    const size_t off_sb  = (off_s8 + (size_t)rows + 255) & ~(size_t)255;
    const size_t sb_words = (size_t)B * 64 * 512;     // == 2*rows
    const size_t off_zA  = (off_sb + sb_words * 4 + 255) & ~(size_t)255;
    const size_t off_tA  = off_zA + (size_t)rows * 4;
    const size_t off_slA = off_tA + (size_t)rows * 4;
    const size_t off_kl  = off_slA + (size_t)rows * 4;
    const size_t need    = off_kl + (size_t)rows * 4;

    uint8_t* wsb = (uint8_t*)d_ws;
    const bool geom_ok = (S == SSAM) && (rows % N == 0) &&
                         (rows % ROWS_PER_BLOCK == 0);

    if (ws_size >= need && geom_ok) {
        uint8_t*  key16  = wsb;
        uint8_t*  q16    = wsb + off_q16;
        uint8_t*  seg8   = wsb + off_s8;
        uint32_t* segbit = (uint32_t*)(wsb + off_sb);
        float*    zA     = (float*)(wsb + off_zA);
        float*    tA     = (float*)(wsb + off_tA);
        float*    slA    = (float*)(wsb + off_slA);
        float*    wskl   = (float*)(wsb + off_kl);

        prep_kernel<<<(rows + 255) / 256, 256, 0, stream>>>(
            key_f, query_f, seg32, key16, q16, seg8, segbit, N, rows, scale);
        segbit_build<<<(rows + 255) / 256, 256, 0, stream>>>(
            seg32, segbit, N, rows);
        dense_local<<<B * 256, 256, 0, stream>>>(
            key16, q16, seg8, out, zA, tA, slA);
        affinity_rand<<<rows / ROWS_PER_BLOCK, 256, 0, stream>>>(
            inds, key16, q16, seg32, segbit, zA, tA, slA, out, wskl);
        loss_reduce<<<1, 1024, 0, stream>>>(wskl, seg32, out + (size_t)rows * S, rows);
    } else {
        float* wskl = (float*)d_ws;
        affinity_fallback<<<rows, 256, 0, stream>>>(
            key_f, query_f, seg32, inds, out, wskl, N, S, scale);
        loss_reduce_fb_dummy:;
        loss_reduce<<<1, 1024, 0, stream>>>(wskl, seg32, out + (size_t)rows * S, rows);
    }
}